// Round 1
// baseline (184.340 us; speedup 1.0000x reference)
//
#include <hip/hip_runtime.h>
#include <hip/hip_bf16.h>

typedef __attribute__((ext_vector_type(8))) short bf16x8;
typedef __attribute__((ext_vector_type(4))) float f32x4;

__device__ __forceinline__ short f2bf(float f) {
    __hip_bfloat16 h = __float2bfloat16(f);
    short s;
    __builtin_memcpy(&s, &h, 2);
    return s;
}

__device__ __forceinline__ float lrelu(float v) {
    // leaky_relu(x, 0.05) == max(x, 0.05*x) since slope in (0,1)
    return fmaxf(v, 0.05f * v);
}

#define MFMA(a, b, c) __builtin_amdgcn_mfma_f32_16x16x32_bf16((a), (b), (c), 0, 0, 0)

// Per wave: one n-group (32 positions). Computes h1^T = W1 * X^T (64x32),
// h2^T = W2 * lrelu(h1^T) (64x32), tracks max over positions, writes 128 outs.
// k-slot convention (both operands, both GEMMs): group g = lane>>4 holds
// k_local = {4g+i | i<4} u {16+4g+(i-4) | i>=4}  -- matches C/D row ownership
// (row = 4*(lane>>4)+reg) so GEMM1's D feeds GEMM2's B in-register.
__global__ __launch_bounds__(256) void neigh_enco_kernel(
    const float* __restrict__ z,
    const int* __restrict__ neigh,
    const float* __restrict__ w1,
    const float* __restrict__ w2,
    float* __restrict__ out,
    int n_rows, int z_rows)
{
    const int lane = threadIdx.x & 63;
    const int g = lane >> 4;     // k-slot group
    const int u = lane & 15;     // fragment row (A) / col (B)
    const int waves_per_blk = blockDim.x >> 6;
    const int wave = blockIdx.x * waves_per_blk + (threadIdx.x >> 6);
    const int nwaves = gridDim.x * waves_per_blk;

    // ---- weight fragments, resident across the n-loop ----
    bf16x8 w1f[4][4];   // [o-block 16][k-step 32] over C=128
    #pragma unroll
    for (int b = 0; b < 4; ++b) {
        #pragma unroll
        for (int s = 0; s < 4; ++s) {
            const float* p = w1 + (16 * b + u) * 128 + 32 * s + 4 * g;
            float4 lo = *reinterpret_cast<const float4*>(p);
            float4 hi = *reinterpret_cast<const float4*>(p + 16);
            bf16x8 f;
            f[0] = f2bf(lo.x); f[1] = f2bf(lo.y); f[2] = f2bf(lo.z); f[3] = f2bf(lo.w);
            f[4] = f2bf(hi.x); f[5] = f2bf(hi.y); f[6] = f2bf(hi.z); f[7] = f2bf(hi.w);
            w1f[b][s] = f;
        }
    }
    bf16x8 w2f[4][2];   // [o2-block 16][k-step 32] over K=64
    #pragma unroll
    for (int b = 0; b < 4; ++b) {
        #pragma unroll
        for (int s = 0; s < 2; ++s) {
            const float* p = w2 + (16 * b + u) * 64 + 32 * s + 4 * g;
            float4 lo = *reinterpret_cast<const float4*>(p);
            float4 hi = *reinterpret_cast<const float4*>(p + 16);
            bf16x8 f;
            f[0] = f2bf(lo.x); f[1] = f2bf(lo.y); f[2] = f2bf(lo.z); f[3] = f2bf(lo.w);
            f[4] = f2bf(hi.x); f[5] = f2bf(hi.y); f[6] = f2bf(hi.z); f[7] = f2bf(hi.w);
            w2f[b][s] = f;
        }
    }

    const unsigned zu = (unsigned)z_rows;

    for (int n = wave; n < n_rows; n += nwaves) {
        // indices for this wave's two position-tiles (col = 16*t + u)
        int i0 = neigh[n * 32 + u];
        int i1 = neigh[n * 32 + 16 + u];
        unsigned r0 = (unsigned)i0 - 1u;  // index 0 (pad row) wraps to huge
        unsigned r1 = (unsigned)i1 - 1u;

        // gather X^T B-fragments: bx[t][s], col m = 16t+u, k per slot convention
        bf16x8 bx[2][4];
        #pragma unroll
        for (int t = 0; t < 2; ++t) {
            unsigned r = t ? r1 : r0;
            bool valid = r < zu;
            const float* base = z + (size_t)r * 128 + 4 * g;
            #pragma unroll
            for (int s = 0; s < 4; ++s) {
                float4 lo = make_float4(0.f, 0.f, 0.f, 0.f);
                float4 hi = make_float4(0.f, 0.f, 0.f, 0.f);
                if (valid) {
                    lo = *reinterpret_cast<const float4*>(base + 32 * s);
                    hi = *reinterpret_cast<const float4*>(base + 32 * s + 16);
                }
                bf16x8 f;
                f[0] = f2bf(lo.x); f[1] = f2bf(lo.y); f[2] = f2bf(lo.z); f[3] = f2bf(lo.w);
                f[4] = f2bf(hi.x); f[5] = f2bf(hi.y); f[6] = f2bf(hi.z); f[7] = f2bf(hi.w);
                bx[t][s] = f;
            }
        }

        f32x4 d2[4][2];
        #pragma unroll
        for (int b2 = 0; b2 < 4; ++b2) {
            d2[b2][0] = (f32x4){0.f, 0.f, 0.f, 0.f};
            d2[b2][1] = (f32x4){0.f, 0.f, 0.f, 0.f};
        }

        float mh1[4][4];  // [o-block][reg] running h1 max (per-lane partial)

        #pragma unroll
        for (int s2 = 0; s2 < 2; ++s2) {
            bf16x8 p2[2];  // GEMM2 B-operand for this k-step, per position-tile
            #pragma unroll
            for (int h = 0; h < 2; ++h) {
                const int b = 2 * s2 + h;   // h1 o-block = GEMM2 k-halfblock
                f32x4 d1[2];
                d1[0] = (f32x4){0.f, 0.f, 0.f, 0.f};
                d1[1] = (f32x4){0.f, 0.f, 0.f, 0.f};
                #pragma unroll
                for (int s = 0; s < 4; ++s) {
                    d1[0] = MFMA(w1f[b][s], bx[0][s], d1[0]);
                    d1[1] = MFMA(w1f[b][s], bx[1][s], d1[1]);
                }
                // leaky relu, feed GEMM2 operand, track h1 max
                #pragma unroll
                for (int t = 0; t < 2; ++t) {
                    #pragma unroll
                    for (int q = 0; q < 4; ++q) {
                        float v = lrelu(d1[t][q]);
                        d1[t][q] = v;
                        p2[t][4 * h + q] = f2bf(v);  // slot i<4 -> b even, i>=4 -> b odd
                    }
                }
                #pragma unroll
                for (int q = 0; q < 4; ++q)
                    mh1[b][q] = fmaxf(d1[0][q], d1[1][q]);
            }
            #pragma unroll
            for (int b2 = 0; b2 < 4; ++b2) {
                d2[b2][0] = MFMA(w2f[b2][s2], p2[0], d2[b2][0]);
                d2[b2][1] = MFMA(w2f[b2][s2], p2[1], d2[b2][1]);
            }
        }

        float mh2[4][4];
        #pragma unroll
        for (int b2 = 0; b2 < 4; ++b2) {
            #pragma unroll
            for (int q = 0; q < 4; ++q)
                mh2[b2][q] = fmaxf(lrelu(d2[b2][0][q]), lrelu(d2[b2][1][q]));
        }

        // max over positions: butterfly across the 16 lanes of each k-group
        #pragma unroll
        for (int m = 1; m <= 8; m <<= 1) {
            #pragma unroll
            for (int b = 0; b < 4; ++b) {
                #pragma unroll
                for (int q = 0; q < 4; ++q) {
                    mh1[b][q] = fmaxf(mh1[b][q], __shfl_xor(mh1[b][q], m, 64));
                    mh2[b][q] = fmaxf(mh2[b][q], __shfl_xor(mh2[b][q], m, 64));
                }
            }
        }

        // lane u writes feature o = 16*(u>>2) + 4g + (u&3)  (all 128 covered)
        float v1s = mh1[0][0], v2s = mh2[0][0];
        #pragma unroll
        for (int j = 1; j < 16; ++j) {
            if (u == j) { v1s = mh1[j >> 2][j & 3]; v2s = mh2[j >> 2][j & 3]; }
        }
        const int o = 16 * (u >> 2) + 4 * g + (u & 3);
        float* op = out + (size_t)n * 128 + o;
        op[0]  = v1s;   // h1 half: features 0..63
        op[64] = v2s;   // h2 half: features 64..127
    }
}

extern "C" void kernel_launch(void* const* d_in, const int* in_sizes, int n_in,
                              void* d_out, int out_size, void* d_ws, size_t ws_size,
                              hipStream_t stream) {
    const float* z     = (const float*)d_in[0];
    const int*   neigh = (const int*)d_in[1];
    const float* w1    = (const float*)d_in[2];
    const float* w2    = (const float*)d_in[3];
    float* out = (float*)d_out;
    const int z_rows = in_sizes[0] / 128;
    const int n_rows = in_sizes[1] / 32;

    dim3 grid(1024), block(256);
    hipLaunchKernelGGL(neigh_enco_kernel, grid, block, 0, stream,
                       z, neigh, w1, w2, out, n_rows, z_rows);
}

// Round 2
// 166.522 us; speedup vs baseline: 1.1070x; 1.1070x over previous
//
#include <hip/hip_runtime.h>
#include <hip/hip_bf16.h>

typedef __attribute__((ext_vector_type(8))) short bf16x8;
typedef __attribute__((ext_vector_type(4))) short s16x4;
typedef __attribute__((ext_vector_type(4))) float f32x4;

__device__ __forceinline__ short f2bf(float f) {
    __hip_bfloat16 h = __float2bfloat16(f);
    short s;
    __builtin_memcpy(&s, &h, 2);
    return s;
}

__device__ __forceinline__ float lrelu(float v) {
    // leaky_relu(x, 0.05) == max(x, 0.05*x) since slope in (0,1)
    return fmaxf(v, 0.05f * v);
}

#define MFMA(a, b, c) __builtin_amdgcn_mfma_f32_16x16x32_bf16((a), (b), (c), 0, 0, 0)

// Per wave: one n (32 positions = 2 col-tiles). h1^T = W1*X^T (64x32),
// h2^T = W2*lrelu(h1^T) (64x32), max over positions, write 128 features.
// k-slot convention (both GEMMs): group g=lane>>4 holds k_local =
// {4g+i | i<4} u {16+4g+(i-4) | i>=4} — matches C/D row = 4g+reg, so
// GEMM1's D feeds GEMM2's B in-register.
// Weights live in LDS in fragment order: frag f, lane l at byte f*1024+l*16
// (contiguous per wave -> conflict-free ds_read_b128, imm offsets).
__global__ __launch_bounds__(256, 3) void neigh_enco_kernel(
    const float* __restrict__ z,
    const int* __restrict__ neigh,
    const float* __restrict__ w1,
    const float* __restrict__ w2,
    float* __restrict__ out,
    int n_rows, int z_rows)
{
    __shared__ __align__(16) short wlds[12288];   // 16 w1 frags + 8 w2 frags, 24 KB

    const int tid = threadIdx.x;
    const int lane = tid & 63;
    const int g = lane >> 4;     // k-slot group
    const int u = lane & 15;     // fragment row (A) / col (B)

    // ---- one-time: convert w1,w2 fp32 -> bf16 fragments in LDS ----
    // 3072 float4 chunks total (w1: 2048, w2: 1024); 12 per thread.
    #pragma unroll
    for (int j = 0; j < 12; ++j) {
        const int c = tid + (j << 8);
        const float* src;
        int row, col, fbase;
        if (c < 2048) {            // w1: 64 rows x 128 cols
            row = c >> 5; col = (c & 31) << 2;
            src = w1 + row * 128 + col;
            fbase = ((row >> 4) << 2) + (col >> 5);          // b*4 + s
        } else {                   // w2: 64 rows x 64 cols
            const int c2 = c - 2048;
            row = c2 >> 4; col = (c2 & 15) << 2;
            src = w2 + row * 64 + col;
            fbase = 16 + ((row >> 4) << 1) + (col >> 5);     // 16 + b*2 + s
        }
        const int rem = col & 31;
        const int gg = (rem >> 2) & 3;
        const int eh = rem >> 4;           // 0: e=0..3, 1: e=4..7
        float4 v = *reinterpret_cast<const float4*>(src);
        s16x4 p;
        p[0] = f2bf(v.x); p[1] = f2bf(v.y); p[2] = f2bf(v.z); p[3] = f2bf(v.w);
        const int idx = ((fbase << 6) + (gg << 4) + (row & 15)) * 8 + (eh << 2);
        *reinterpret_cast<s16x4*>(&wlds[idx]) = p;
    }
    __syncthreads();

    const bf16x8* __restrict__ wv = reinterpret_cast<const bf16x8*>(wlds);

    const int waves_per_blk = blockDim.x >> 6;
    const int wave = blockIdx.x * waves_per_blk + (tid >> 6);
    const int nwaves = gridDim.x * waves_per_blk;
    const unsigned zu = (unsigned)z_rows;

    // index prefetch (breaks idx->gather serial chain across iterations)
    int n = wave;
    int pi0 = 0, pi1 = 0;
    if (n < n_rows) {
        pi0 = neigh[n * 32 + u];
        pi1 = neigh[n * 32 + 16 + u];
    }

    for (; n < n_rows; n += nwaves) {
        unsigned r0 = (unsigned)pi0 - 1u;   // pad row 0 wraps to huge
        unsigned r1 = (unsigned)pi1 - 1u;
        const int nn = n + nwaves;
        if (nn < n_rows) {
            pi0 = neigh[nn * 32 + u];
            pi1 = neigh[nn * 32 + 16 + u];
        }

        // gather X^T B-fragments: bx[t][s], col m = 16t+u
        bf16x8 bx[2][4];
        #pragma unroll
        for (int t = 0; t < 2; ++t) {
            const unsigned r = t ? r1 : r0;
            const bool valid = r < zu;
            const float* base = z + (size_t)r * 128 + 4 * g;
            #pragma unroll
            for (int s = 0; s < 4; ++s) {
                float4 lo = make_float4(0.f, 0.f, 0.f, 0.f);
                float4 hi = make_float4(0.f, 0.f, 0.f, 0.f);
                if (valid) {
                    lo = *reinterpret_cast<const float4*>(base + 32 * s);
                    hi = *reinterpret_cast<const float4*>(base + 32 * s + 16);
                }
                bf16x8 f;
                f[0] = f2bf(lo.x); f[1] = f2bf(lo.y); f[2] = f2bf(lo.z); f[3] = f2bf(lo.w);
                f[4] = f2bf(hi.x); f[5] = f2bf(hi.y); f[6] = f2bf(hi.z); f[7] = f2bf(hi.w);
                bx[t][s] = f;
            }
        }

        f32x4 d2[4][2];
        #pragma unroll
        for (int b2 = 0; b2 < 4; ++b2) {
            d2[b2][0] = (f32x4){0.f, 0.f, 0.f, 0.f};
            d2[b2][1] = (f32x4){0.f, 0.f, 0.f, 0.f};
        }

        float V1[16], V2[16];   // per-lane position-max partials, idx = b*4+q

        #pragma unroll
        for (int s2 = 0; s2 < 2; ++s2) {
            bf16x8 p2[2];
            #pragma unroll
            for (int h = 0; h < 2; ++h) {
                const int b = 2 * s2 + h;   // h1 o-block = GEMM2 k-halfblock
                f32x4 d1[2];
                d1[0] = (f32x4){0.f, 0.f, 0.f, 0.f};
                d1[1] = (f32x4){0.f, 0.f, 0.f, 0.f};
                #pragma unroll
                for (int s = 0; s < 4; ++s) {
                    const bf16x8 wf = wv[((b << 2) + s) * 64 + lane];
                    d1[0] = MFMA(wf, bx[0][s], d1[0]);
                    d1[1] = MFMA(wf, bx[1][s], d1[1]);
                }
                #pragma unroll
                for (int t = 0; t < 2; ++t) {
                    #pragma unroll
                    for (int q = 0; q < 4; ++q) {
                        float v = lrelu(d1[t][q]);
                        d1[t][q] = v;
                        p2[t][4 * h + q] = f2bf(v);
                    }
                }
                #pragma unroll
                for (int q = 0; q < 4; ++q)
                    V1[b * 4 + q] = fmaxf(d1[0][q], d1[1][q]);
            }
            #pragma unroll
            for (int b2 = 0; b2 < 4; ++b2) {
                const bf16x8 wf = wv[1024 + ((b2 << 1) + s2) * 64 + lane];
                d2[b2][0] = MFMA(wf, p2[0], d2[b2][0]);
                d2[b2][1] = MFMA(wf, p2[1], d2[b2][1]);
            }
        }

        #pragma unroll
        for (int b2 = 0; b2 < 4; ++b2) {
            #pragma unroll
            for (int q = 0; q < 4; ++q)
                V2[b2 * 4 + q] = fmaxf(lrelu(d2[b2][0][q]), lrelu(d2[b2][1][q]));
        }

        // halving-fold max over the 16 lanes of each k-group:
        // round k keeps values whose index bit k matches lane bit k.
        // After 4 rounds lane u holds V[u] -> (b,q) = (u>>2, u&3).
        #pragma unroll
        for (int k = 0; k < 4; ++k) {
            const int m = 1 << k;
            const bool hi = (u & m) != 0;
            #pragma unroll
            for (int j = 0; j < (8 >> k); ++j) {
                float k1 = hi ? V1[2 * j + 1] : V1[2 * j];
                float s1 = hi ? V1[2 * j] : V1[2 * j + 1];
                float k2 = hi ? V2[2 * j + 1] : V2[2 * j];
                float s2v = hi ? V2[2 * j] : V2[2 * j + 1];
                V1[j] = fmaxf(k1, __shfl_xor(s1, m, 64));
                V2[j] = fmaxf(k2, __shfl_xor(s2v, m, 64));
            }
        }

        // lane (g,u) owns feature o = 16*(u>>2) + 4g + (u&3)
        const int o = 16 * (u >> 2) + 4 * g + (u & 3);
        float* op = out + (size_t)n * 128 + o;
        op[0]  = V1[0];   // h1 half: features 0..63
        op[64] = V2[0];   // h2 half: features 64..127
    }
}

extern "C" void kernel_launch(void* const* d_in, const int* in_sizes, int n_in,
                              void* d_out, int out_size, void* d_ws, size_t ws_size,
                              hipStream_t stream) {
    const float* z     = (const float*)d_in[0];
    const int*   neigh = (const int*)d_in[1];
    const float* w1    = (const float*)d_in[2];
    const float* w2    = (const float*)d_in[3];
    float* out = (float*)d_out;
    const int z_rows = in_sizes[0] / 128;
    const int n_rows = in_sizes[1] / 32;

    dim3 grid(2048), block(256);
    hipLaunchKernelGGL(neigh_enco_kernel, grid, block, 0, stream,
                       z, neigh, w1, w2, out, n_rows, z_rows);
}